// Round 9
// baseline (107.959 us; speedup 1.0000x reference)
//
#include <hip/hip_runtime.h>
#include <math.h>

#define NN      1024
#define NB      8
#define NLAYERS 55

// ---------------- lane-XOR exchange primitives (distance D in lanes) --------
template<int CTRL>
__device__ __forceinline__ float dpp_xor(float y) {
    int i = __builtin_bit_cast(int, y);
    i = __builtin_amdgcn_update_dpp(i, i, CTRL, 0xF, 0xF, false);
    return __builtin_bit_cast(float, i);
}
template<int OFF>
__device__ __forceinline__ float swz_xor(float y) {
    int i = __builtin_bit_cast(int, y);
    i = __builtin_amdgcn_ds_swizzle(i, OFF);
    return __builtin_bit_cast(float, i);
}
template<int D> __device__ __forceinline__ float lshuf(float y) {
    if constexpr      (D == 1)  return dpp_xor<0xB1>(y);       // quad_perm 1,0,3,2
    else if constexpr (D == 2)  return dpp_xor<0x4E>(y);       // quad_perm 2,3,0,1
    else if constexpr (D == 4)  return swz_xor<0x101F>(y);
    else if constexpr (D == 8)  return swz_xor<0x201F>(y);
    else if constexpr (D == 16) return swz_xor<0x401F>(y);
    else                        return __shfl_xor(y, 32, 64);  // lane^32
}
// producer layout (4 cols/lane): column distance M -> lane ^ (M/4)
template<int M> __device__ __forceinline__ float shufp(float y) {
    if constexpr      (M == 4)   return dpp_xor<0xB1>(y);
    else if constexpr (M == 8)   return dpp_xor<0x4E>(y);
    else if constexpr (M == 16)  return swz_xor<0x101F>(y);
    else if constexpr (M == 32)  return swz_xor<0x201F>(y);
    else if constexpr (M == 64)  return swz_xor<0x401F>(y);
    else                         return __shfl_xor(y, 32, 64);
}

__device__ __forceinline__ float bxor(float v, int mask) {
    return __builtin_bit_cast(float, __builtin_bit_cast(int, v) ^ mask);
}
__device__ __forceinline__ float sigm(float d) {
    const float ad = fabsf(d) + 1e-10f;
    const float pw = __expf(-0.25f * __logf(ad));   // (|d|+eps)^-0.25
    const float z  = d * 10.0f * pw;
    return __builtin_amdgcn_rcpf(1.0f + __expf(-z));
}

// ================= Producer: 1 block/batch, 4 cols/lane, fully unrolled =====
__device__ __forceinline__ void pairup(float (&x)[4], float (&alv)[4],
                                       int jl, int jh, int sw) {
    const float lo = x[jl], hi = x[jh];
    const float dv = hi - lo;
    const float a  = sigm(bxor(dv, sw << 31));   // sigm(v_b - v_a)
    alv[jl] = a; alv[jh] = a;
    x[jl] = fmaf(-a, dv, hi);    // a*lo + (1-a)*hi
    x[jh] = fmaf( a, dv, lo);    // (1-a)*lo + a*hi
}
template<int M>
__device__ __forceinline__ void crossup(float (&x)[4], float (&alv)[4],
                                        int c0, int t) {
    constexpr int S = (M==4)?2:(M==8)?3:(M==16)?4:(M==32)?5:(M==64)?6:7;
    const int flip = ((((c0 >> S) & 1) ^ ((c0 >> t) & 1)) << 31);
    #pragma unroll
    for (int j = 0; j < 4; ++j) {
        const float xq = shufp<M>(x[j]);
        const float dv = xq - x[j];
        const float a  = sigm(bxor(dv, flip));
        alv[j] = a;
        x[j]   = fmaf(a, x[j] - xq, xq);
    }
}
template<int S, int T>
__device__ __forceinline__ void produce_layer(float (&x)[4], float (&alv)[4],
                                              int c0, float* xs) {
    if constexpr (S == 0) {
        pairup(x, alv, 0, 1, ((c0 + 0) >> T) & 1);
        pairup(x, alv, 2, 3, ((c0 + 2) >> T) & 1);
    } else if constexpr (S == 1) {
        pairup(x, alv, 0, 2, ((c0 + 0) >> T) & 1);
        pairup(x, alv, 1, 3, ((c0 + 1) >> T) & 1);
    } else if constexpr (S <= 7) {
        crossup<(1 << S)>(x, alv, c0, T);
    } else {                         // S = 8,9 : LDS bounce
        constexpr int m = 1 << S;
        __syncthreads();
        *(float4*)&xs[c0] = *(float4*)&x[0];
        __syncthreads();
        float xq[4];
        *(float4*)&xq[0] = *(const float4*)&xs[c0 ^ m];
        const int flip = ((((c0 >> S) & 1) ^ ((c0 >> T) & 1)) << 31);
        #pragma unroll
        for (int j = 0; j < 4; ++j) {
            const float dv = xq[j] - x[j];
            const float a  = sigm(bxor(dv, flip));
            alv[j] = a;
            x[j]   = fmaf(a, x[j] - xq[j], xq[j]);
        }
    }
}
// phase-matched alpha store: consumer (lane,j) of width W=64K reads
// slab[(col&~(W-1)) + (col&63)*K + j]  -> write alpha(col) there.
template<int K>
__device__ __forceinline__ void storeA(float* slab, int c0, const float (&alv)[4]) {
    float* p = slab + (c0 & ~(64*K - 1)) + (c0 & 63) * K + ((c0 >> 6) & (K - 1));
    p[0]   = alv[0];
    p[K]   = alv[1];
    p[2*K] = alv[2];
    p[3*K] = alv[3];
}

__global__ __launch_bounds__(256) void diffsort_alpha5(
    const float* __restrict__ vecs,
    float*       __restrict__ out,
    float*       __restrict__ al_g)
{
    __shared__ float xs[NN];
    const int tid   = threadIdx.x;
    const int batch = blockIdx.x;
    const int c0    = tid * 4;

    float x[4];
    *(float4*)&x[0] = *(const float4*)(vecs + batch * NN + c0);

    float* slab = al_g + (size_t)batch * NLAYERS * NN;
    float alv[4];
    #define PL(B, S, K)                                 \
        produce_layer<S, B + 1>(x, alv, c0, xs);        \
        storeA<K>(slab, c0, alv);                       \
        slab += NN;
    PL(0,0,2)
    PL(1,1,2) PL(1,0,2)
    PL(2,2,2) PL(2,1,2) PL(2,0,2)
    PL(3,3,2) PL(3,2,2) PL(3,1,2) PL(3,0,2)
    PL(4,4,2) PL(4,3,2) PL(4,2,2) PL(4,1,2) PL(4,0,2)
    PL(5,5,2) PL(5,4,2) PL(5,3,2) PL(5,2,2) PL(5,1,2) PL(5,0,2)
    PL(6,6,2) PL(6,5,2) PL(6,4,2) PL(6,3,2) PL(6,2,2) PL(6,1,2) PL(6,0,2)
    PL(7,7,4) PL(7,6,4) PL(7,5,4) PL(7,4,4) PL(7,3,4) PL(7,2,4) PL(7,1,4) PL(7,0,4)
    PL(8,8,8) PL(8,7,8) PL(8,6,8) PL(8,5,8) PL(8,4,8) PL(8,3,8) PL(8,2,8) PL(8,1,8) PL(8,0,8)
    PL(9,9,16) PL(9,8,16) PL(9,7,16) PL(9,6,16) PL(9,5,16)
    PL(9,4,16) PL(9,3,16) PL(9,2,16) PL(9,1,16) PL(9,0,16)
    #undef PL

    *(float4*)(out + batch * NN + c0) = *(float4*)&x[0];
}

// ============ Consumer: progressive-width rows, 4 rows/wave, prefetch =======
template<int W64, int DJ>
__device__ __forceinline__ void pairJ(float (&v)[4][16], const float (&al)[W64]) {
    #pragma unroll
    for (int r = 0; r < 4; ++r)
        #pragma unroll
        for (int j = 0; j < W64; ++j)
            if ((j & DJ) == 0) {
                const int jl = j, jh = j | DJ;
                const float a  = al[jl];            // == al[jh]
                const float dv = v[r][jl] - v[r][jh];
                const float lo = v[r][jl];
                v[r][jl] = fmaf( a, dv, v[r][jh]);  // a*lo + (1-a)*hi
                v[r][jh] = fmaf(-a, dv, lo);
            }
}
template<int W64, int D>
__device__ __forceinline__ void laneX(float (&v)[4][16], const float (&al)[W64]) {
    #pragma unroll
    for (int r = 0; r < 4; ++r)
        #pragma unroll
        for (int j = 0; j < W64; ++j) {
            const float p = lshuf<D>(v[r][j]);
            v[r][j] = fmaf(al[j], v[r][j] - p, p);
        }
}
__device__ __forceinline__ void ld8(float* d, const float* s) {
    *(float4*)d       = *(const float4*)s;
    *(float4*)(d + 4) = *(const float4*)(s + 4);
}
__device__ __forceinline__ void ld16(float* d, const float* s) {
    ld8(d, s); ld8(d + 8, s + 8);
}

__global__ __launch_bounds__(256) void diffsort_rows4(
    const float* __restrict__ al_g,
    float*       __restrict__ out)
{
    const int tid   = threadIdx.x;
    const int lane  = tid & 63;
    const int wave  = tid >> 6;
    const int batch = blockIdx.x & 7;       // XCD-aligned with producer
    const int rgrp  = blockIdx.x >> 3;      // 64 groups of 16 rows per batch
    const int R0    = rgrp * 16 + wave * 4; // 4 rows per wave
    const int WA    = (R0 >> 7) << 7;
    const int W7    = (R0 >> 8) << 8;
    const int W8    = (R0 >> 9) << 9;

    float v[4][16];
    #pragma unroll
    for (int r = 0; r < 4; ++r) {
        const int loc = (R0 + r) & 127;
        v[r][0] = (loc == lane)      ? 1.0f : 0.0f;
        v[r][1] = (loc == lane + 64) ? 1.0f : 0.0f;
        #pragma unroll
        for (int j = 2; j < 16; ++j) v[r][j] = 0.0f;
    }

    const float* baseg = al_g + (size_t)batch * NLAYERS * NN;

    // ---- Phase A: layers 0..27, width 128 (j 0..1), float2 alpha ----
    {
        const float* apA = baseg + WA + lane * 2;
        float alA[2], alB[2];
        *(float2*)alA = *(const float2*)apA;
        #define AX(CUR, NXT, D, LAST) do {                                    \
            if (!(LAST)) *(float2*)(NXT) = *(const float2*)(apA + NN);        \
            laneX<2, D>(v, CUR);  apA += NN; } while (0);
        #define AJ(CUR, NXT, DJ, LAST) do {                                   \
            if (!(LAST)) *(float2*)(NXT) = *(const float2*)(apA + NN);        \
            pairJ<2, DJ>(v, CUR); apA += NN; } while (0);
        AX(alA, alB, 1, 0)
        AX(alB, alA, 2, 0) AX(alA, alB, 1, 0)
        AX(alB, alA, 4, 0) AX(alA, alB, 2, 0) AX(alB, alA, 1, 0)
        AX(alA, alB, 8, 0) AX(alB, alA, 4, 0) AX(alA, alB, 2, 0) AX(alB, alA, 1, 0)
        AX(alA, alB,16, 0) AX(alB, alA, 8, 0) AX(alA, alB, 4, 0) AX(alB, alA, 2, 0)
        AX(alA, alB, 1, 0)
        AX(alB, alA,32, 0) AX(alA, alB,16, 0) AX(alB, alA, 8, 0) AX(alA, alB, 4, 0)
        AX(alB, alA, 2, 0) AX(alA, alB, 1, 0)
        AJ(alB, alA, 1, 0) AX(alA, alB,32, 0) AX(alB, alA,16, 0) AX(alA, alB, 8, 0)
        AX(alB, alA, 4, 0) AX(alA, alB, 2, 0) AX(alB, alA, 1, 1)
        #undef AX
        #undef AJ
    }

    // ---- widen to 256 ----
    if (WA & 128) {
        #pragma unroll
        for (int r = 0; r < 4; ++r) {
            v[r][2] = v[r][0]; v[r][3] = v[r][1];
            v[r][0] = 0.0f;    v[r][1] = 0.0f;
        }
    }

    // ---- Block 7: layers 28..35, width 256 (j 0..3), float4 alpha ----
    {
        const float* apB = baseg + 28 * NN + W7 + lane * 4;
        float alC[4], alD[4];
        *(float4*)alC = *(const float4*)apB;
        #define BX(CUR, NXT, D, LAST) do {                                    \
            if (!(LAST)) *(float4*)(NXT) = *(const float4*)(apB + NN);        \
            laneX<4, D>(v, CUR);  apB += NN; } while (0);
        #define BJ(CUR, NXT, DJ, LAST) do {                                   \
            if (!(LAST)) *(float4*)(NXT) = *(const float4*)(apB + NN);        \
            pairJ<4, DJ>(v, CUR); apB += NN; } while (0);
        BJ(alC, alD, 2, 0) BJ(alD, alC, 1, 0)
        BX(alC, alD,32, 0) BX(alD, alC,16, 0) BX(alC, alD, 8, 0) BX(alD, alC, 4, 0)
        BX(alC, alD, 2, 0) BX(alD, alC, 1, 1)
        #undef BX
        #undef BJ
    }

    // ---- widen to 512 ----
    if (W7 & 256) {
        #pragma unroll
        for (int r = 0; r < 4; ++r)
            #pragma unroll
            for (int j = 0; j < 4; ++j) { v[r][j+4] = v[r][j]; v[r][j] = 0.0f; }
    }

    // ---- Block 8: layers 36..44, width 512 (j 0..7), 2x float4 alpha ----
    {
        const float* apC = baseg + 36 * NN + W8 + lane * 8;
        float alE[8], alF[8];
        ld8(alE, apC);
        #define CX(CUR, NXT, D, LAST) do {                                    \
            if (!(LAST)) ld8(NXT, apC + NN);                                  \
            laneX<8, D>(v, CUR);  apC += NN; } while (0);
        #define CJ(CUR, NXT, DJ, LAST) do {                                   \
            if (!(LAST)) ld8(NXT, apC + NN);                                  \
            pairJ<8, DJ>(v, CUR); apC += NN; } while (0);
        CJ(alE, alF, 4, 0) CJ(alF, alE, 2, 0) CJ(alE, alF, 1, 0)
        CX(alF, alE,32, 0) CX(alE, alF,16, 0) CX(alF, alE, 8, 0) CX(alE, alF, 4, 0)
        CX(alF, alE, 2, 0) CX(alE, alF, 1, 1)
        #undef CX
        #undef CJ
    }

    // ---- widen to 1024 ----
    if (W8 & 512) {
        #pragma unroll
        for (int r = 0; r < 4; ++r)
            #pragma unroll
            for (int j = 0; j < 8; ++j) { v[r][j+8] = v[r][j]; v[r][j] = 0.0f; }
    }

    // ---- Block 9: layers 45..54, width 1024 (j 0..15), 4x float4 alpha ----
    {
        const float* apD = baseg + 45 * NN + lane * 16;
        float alG[16], alH[16];
        ld16(alG, apD);
        #define DX(CUR, NXT, D, LAST) do {                                    \
            if (!(LAST)) ld16(NXT, apD + NN);                                 \
            laneX<16, D>(v, CUR);  apD += NN; } while (0);
        #define DJ_(CUR, NXT, DJ, LAST) do {                                  \
            if (!(LAST)) ld16(NXT, apD + NN);                                 \
            pairJ<16, DJ>(v, CUR); apD += NN; } while (0);
        DJ_(alG, alH, 8, 0) DJ_(alH, alG, 4, 0) DJ_(alG, alH, 2, 0) DJ_(alH, alG, 1, 0)
        DX(alG, alH,32, 0) DX(alH, alG,16, 0) DX(alG, alH, 8, 0) DX(alH, alG, 4, 0)
        DX(alG, alH, 2, 0) DX(alH, alG, 1, 1)
        #undef DX
        #undef DJ_
    }

    // ---- epilogue: col = j*64 + lane ----
    float* Xo = out + (size_t)NB * NN + (size_t)batch * NN * NN;
    #pragma unroll
    for (int r = 0; r < 4; ++r) {
        float* rowp = Xo + (size_t)(R0 + r) * NN + lane;
        #pragma unroll
        for (int j = 0; j < 16; ++j)
            rowp[j * 64] = v[r][j];
    }
}

extern "C" void kernel_launch(void* const* d_in, const int* in_sizes, int n_in,
                              void* d_out, int out_size, void* d_ws, size_t ws_size,
                              hipStream_t stream) {
    const float* vecs = (const float*)d_in[0];
    float*       out  = (float*)d_out;
    float*       al_g = (float*)d_ws;    // NB*NLAYERS*NN*4 = 1.80 MB

    diffsort_alpha5<<<NB, 256, 0, stream>>>(vecs, out, al_g);
    diffsort_rows4<<<NB * 64, 256, 0, stream>>>(al_g, out);
}